// Round 1
// baseline (1270.813 us; speedup 1.0000x reference)
//
#include <hip/hip_runtime.h>
#include <stdint.h>

typedef _Float16 half2_t __attribute__((ext_vector_type(2)));
typedef short bf16x8 __attribute__((ext_vector_type(8)));
typedef float f32x4 __attribute__((ext_vector_type(4)));
typedef unsigned short u16;
typedef unsigned int u32;

#define B_ 64
#define S_ 512
#define D_ 512
#define H_ 512
#define FF_ 1024
#define C_ 1000

__device__ __forceinline__ u16 f2bf(float f){
  u32 u = __builtin_bit_cast(u32, f);
  u = (u + 0x7FFFu + ((u >> 16) & 1u)) >> 16;
  return (u16)u;
}
__device__ __forceinline__ u32 packh2(float a, float b){
  u16 lo = __builtin_bit_cast(u16, (_Float16)a);
  u16 hi = __builtin_bit_cast(u16, (_Float16)b);
  return (u32)lo | ((u32)hi << 16);
}
__device__ __forceinline__ float fdot2u(u32 a, u32 b, float c){
  return __builtin_amdgcn_fdot2(__builtin_bit_cast(half2_t, a),
                                __builtin_bit_cast(half2_t, b), c, false);
}

// ---- P1: gather emb rows by token, convert f32 -> bf16. Xg [32768][512] ----
__global__ void k_gather(const int* __restrict__ tokens, const float* __restrict__ emb,
                         u16* __restrict__ Xg){
  int c = blockIdx.x * 256 + threadIdx.x;      // 2,097,152 chunks of 8 elems
  int row = c >> 6, seg = c & 63;
  int tok = tokens[row];
  const float4* s = (const float4*)(emb + (size_t)tok * 512 + seg * 8);
  float4 a = s[0], b = s[1];
  uint4 o;
  o.x = (u32)f2bf(a.x) | ((u32)f2bf(a.y) << 16);
  o.y = (u32)f2bf(a.z) | ((u32)f2bf(a.w) << 16);
  o.z = (u32)f2bf(b.x) | ((u32)f2bf(b.y) << 16);
  o.w = (u32)f2bf(b.z) | ((u32)f2bf(b.w) << 16);
  *(uint4*)(Xg + (size_t)row * 512 + seg * 8) = o;
}

// ---- P2: transpose+convert Wx [512k][512n] f32 -> WxT [512n][512k] bf16 ----
__global__ void k_trans_cvt(const float* __restrict__ src, u16* __restrict__ dst){
  __shared__ u16 t[64][65];
  int bx = blockIdx.x & 7, by = blockIdx.x >> 3;
  int tid = threadIdx.x;
  int c = tid & 63, r0 = (tid >> 6) * 16;
  #pragma unroll
  for (int i = 0; i < 16; i++){
    int k = by * 64 + r0 + i, n = bx * 64 + c;
    t[r0 + i][c] = f2bf(src[k * 512 + n]);
  }
  __syncthreads();
  #pragma unroll
  for (int i = 0; i < 16; i++){
    int n = bx * 64 + r0 + i, k = by * 64 + c;
    dst[n * 512 + k] = t[c][r0 + i];
  }
}

// ---- P3: Wh f32 [512k][512j] -> packed f16 pairs, split reg-part / LDS-residual ----
// slot s = j*2+q (q = k-half). pair p in [0,128): k = q*256 + 2p.
// p < 100 -> Wreg[p*1024 + s]; else r=p-100 in [0,28): Wres[((r>>2)*1024+s)*4 + (r&3)]
__global__ void k_prep_wh(const float* __restrict__ Wh, u32* __restrict__ Wreg,
                          u32* __restrict__ Wres){
  int x = blockIdx.x * 256 + threadIdx.x;      // 131072
  int kp = x >> 9, j = x & 511;
  float w0 = Wh[(2 * kp) * 512 + j];
  float w1 = Wh[(2 * kp + 1) * 512 + j];
  u32 v = packh2(w0, w1);
  int q = kp >> 7, p = kp & 127, s = j * 2 + q;
  if (p < 100) Wreg[p * 1024 + s] = v;
  else { int r = p - 100; Wres[((r >> 2) * 1024 + s) * 4 + (r & 3)] = v; }
}

// ---- P4: generic pack K-pairs: dst[p*N+n] = half2(src[2p][n], src[2p+1][n]) ----
__global__ void k_pack_pairs(const float* __restrict__ src, u32* __restrict__ dst, int N){
  int n = blockIdx.x * 256 + threadIdx.x;
  int p = blockIdx.y;
  if (n >= N) return;
  dst[p * N + n] = packh2(src[(2 * p) * N + n], src[(2 * p + 1) * N + n]);
}

// ---- G1: xproj = Xg @ Wx + b_rnn, bf16 MFMA, out f16 [32768][512] ----
__global__ __launch_bounds__(256) void k_gemm(const u16* __restrict__ A, const u16* __restrict__ Bt,
                                              const float* __restrict__ bias, u16* __restrict__ out){
  __shared__ __align__(16) u16 As[128 * 40];
  __shared__ __align__(16) u16 Bs[128 * 40];
  int tid = threadIdx.x;
  int m0 = blockIdx.x * 128, n0 = blockIdx.y * 128;
  int w = tid >> 6, l = tid & 63;
  int wr = w >> 1, wc = w & 1;
  int kg = l >> 4, r16 = l & 15;
  f32x4 acc[4][4];
  #pragma unroll
  for (int mi = 0; mi < 4; mi++)
    #pragma unroll
    for (int ni = 0; ni < 4; ni++) acc[mi][ni] = (f32x4){0.f, 0.f, 0.f, 0.f};
  int srow = tid >> 1, spart = tid & 1;
  for (int kt = 0; kt < 512; kt += 32){
    const uint4* sa = (const uint4*)(A + (size_t)(m0 + srow) * 512 + kt);
    uint4 a0 = sa[spart * 2], a1 = sa[spart * 2 + 1];
    const uint4* sb = (const uint4*)(Bt + (size_t)(n0 + srow) * 512 + kt);
    uint4 b0 = sb[spart * 2], b1 = sb[spart * 2 + 1];
    uint4* da = (uint4*)(As + srow * 40 + spart * 16);
    da[0] = a0; da[1] = a1;
    uint4* db = (uint4*)(Bs + srow * 40 + spart * 16);
    db[0] = b0; db[1] = b1;
    __syncthreads();
    bf16x8 af[4], bfr[4];
    #pragma unroll
    for (int mi = 0; mi < 4; mi++)
      af[mi] = *(const bf16x8*)(As + (wr * 64 + mi * 16 + r16) * 40 + kg * 8);
    #pragma unroll
    for (int ni = 0; ni < 4; ni++)
      bfr[ni] = *(const bf16x8*)(Bs + (wc * 64 + ni * 16 + r16) * 40 + kg * 8);
    #pragma unroll
    for (int mi = 0; mi < 4; mi++)
      #pragma unroll
      for (int ni = 0; ni < 4; ni++)
        acc[mi][ni] = __builtin_amdgcn_mfma_f32_16x16x32_bf16(af[mi], bfr[ni], acc[mi][ni], 0, 0, 0);
    __syncthreads();
  }
  #pragma unroll
  for (int ni = 0; ni < 4; ni++){
    int col = n0 + wc * 64 + ni * 16 + r16;
    float bb = bias[col];
    #pragma unroll
    for (int mi = 0; mi < 4; mi++){
      int mb = m0 + wr * 64 + mi * 16 + kg * 4;
      #pragma unroll
      for (int r = 0; r < 4; r++){
        float v = acc[mi][ni][r] + bb;
        out[(size_t)(mb + r) * 512 + col] = __builtin_bit_cast(u16, (_Float16)v);
      }
    }
  }
}

// ---- R: 512-step RNN scan. 64 blocks (1 per batch), 1024 thr. Wh in regs+LDS. ----
// thread: column j = tid>>1, k-half q = tid&1. 100 weight pairs in VGPRs, 28 in LDS.
__global__ __launch_bounds__(1024) void k_rnn(const u32* __restrict__ Wreg, const uint4* __restrict__ Wres,
                                              const u16* __restrict__ xproj, const int* __restrict__ tokens,
                                              u32* __restrict__ hpack){
  __shared__ __align__(16) u32 hbuf[2][256];   // h as packed half2, double-buffered
  __shared__ uint4 wres[7][1024];              // residual weights: 112 KB
  __shared__ int toks[512];
  int b = blockIdx.x, tid = threadIdx.x;
  int q = tid & 1, j = tid >> 1;
  u32 w[100];
  #pragma unroll
  for (int p = 0; p < 100; p++) w[p] = Wreg[p * 1024 + tid];
  #pragma unroll
  for (int c = 0; c < 7; c++) wres[c][tid] = Wres[c * 1024 + tid];
  if (tid < 512) toks[tid] = tokens[b * 512 + tid];
  if (tid < 256) hbuf[0][tid] = 0;
  __syncthreads();
  const u16* xp = xproj + (size_t)b * S_ * H_;
  u32 hword = 0;
  u16 xpn = xp[j];
  for (int t = 0; t < 512; t++){
    u16 xpc = xpn;
    if (t < 511) xpn = xp[(t + 1) * 512 + j];   // prefetch next step's input
    const uint4* hv4 = (const uint4*)(&hbuf[t & 1][q * 128]);
    float a0 = 0.f, a1 = 0.f, a2 = 0.f, a3 = 0.f;
    #pragma unroll
    for (int c = 0; c < 25; c++){
      uint4 hv = hv4[c];
      a0 = fdot2u(w[4 * c + 0], hv.x, a0);
      a1 = fdot2u(w[4 * c + 1], hv.y, a1);
      a2 = fdot2u(w[4 * c + 2], hv.z, a2);
      a3 = fdot2u(w[4 * c + 3], hv.w, a3);
    }
    #pragma unroll
    for (int c = 0; c < 7; c++){
      uint4 hv = hv4[25 + c];
      uint4 wv = wres[c][tid];
      a0 = fdot2u(wv.x, hv.x, a0);
      a1 = fdot2u(wv.y, hv.y, a1);
      a2 = fdot2u(wv.z, hv.z, a2);
      a3 = fdot2u(wv.w, hv.w, a3);
    }
    float sum = (a0 + a2) + (a1 + a3);
    sum += __shfl_xor(sum, 1);                  // combine the two k-halves of col j
    float hn = (float)__builtin_bit_cast(_Float16, xpc) + sum;
    hn = fmaxf(hn, 0.f);
    float ho = __shfl_xor(hn, 2);               // neighbor column's value
    if (toks[t] != 0) hword = packh2(hn, ho);   // masked step: keep previous hword
    if ((tid & 3) == 0) hbuf[(t + 1) & 1][tid >> 2] = hword;
    __syncthreads();
  }
  if (tid < 256) hpack[b * 256 + tid] = hbuf[0][tid];
}

// ---- H1: y1 = relu(h @ W1 + b1), packed output ----
__global__ __launch_bounds__(256) void k_fc1(const u32* __restrict__ hpack, const u32* __restrict__ W1p,
                                             const float* __restrict__ b1, u32* __restrict__ y1p){
  __shared__ u32 hrow[256];
  int b = blockIdx.y, tid = threadIdx.x;
  int n = blockIdx.x * 256 + tid;
  hrow[tid] = hpack[b * 256 + tid];
  __syncthreads();
  float a0 = 0.f, a1 = 0.f;
  #pragma unroll 8
  for (int p = 0; p < 256; p += 2){
    a0 = fdot2u(W1p[p * FF_ + n], hrow[p], a0);
    a1 = fdot2u(W1p[(p + 1) * FF_ + n], hrow[p + 1], a1);
  }
  float acc = fmaxf(a0 + a1 + b1[n], 0.f);
  float other = __shfl_xor(acc, 1);
  if ((tid & 1) == 0) y1p[b * 512 + (n >> 1)] = packh2(acc, other);
}

// ---- H2: y2 = relu(y1 @ W2 + b2), packed output ----
__global__ __launch_bounds__(256) void k_fc2(const u32* __restrict__ y1p, const u32* __restrict__ W2p,
                                             const float* __restrict__ b2, u32* __restrict__ y2p){
  __shared__ u32 yrow[512];
  int b = blockIdx.y, tid = threadIdx.x;
  int n = blockIdx.x * 256 + tid;
  yrow[tid] = y1p[b * 512 + tid];
  yrow[tid + 256] = y1p[b * 512 + 256 + tid];
  __syncthreads();
  float a0 = 0.f, a1 = 0.f;
  #pragma unroll 8
  for (int p = 0; p < 512; p += 2){
    a0 = fdot2u(W2p[p * FF_ + n], yrow[p], a0);
    a1 = fdot2u(W2p[(p + 1) * FF_ + n], yrow[p + 1], a1);
  }
  float acc = fmaxf(a0 + a1 + b2[n], 0.f);
  float other = __shfl_xor(acc, 1);
  if ((tid & 1) == 0) y2p[b * 512 + (n >> 1)] = packh2(acc, other);
}

// ---- H3: z = y2 @ Wo + bo, softmax, write f32 output [64][1000] ----
__global__ __launch_bounds__(256) void k_out(const u32* __restrict__ y2p, const u32* __restrict__ Wop,
                                             const float* __restrict__ bo, float* __restrict__ out){
  __shared__ u32 yrow[512];
  __shared__ float redm[4], reds[4];
  int b = blockIdx.x, tid = threadIdx.x;
  yrow[tid] = y2p[b * 512 + tid];
  yrow[tid + 256] = y2p[b * 512 + 256 + tid];
  __syncthreads();
  int n0 = tid, n1 = tid + 256, n2 = tid + 512, n3 = tid + 768;
  bool v3 = n3 < C_;
  int n3c = v3 ? n3 : 0;
  float z0 = 0.f, z1 = 0.f, z2 = 0.f, z3 = 0.f;
  #pragma unroll 4
  for (int p = 0; p < 512; p++){
    u32 y = yrow[p];
    z0 = fdot2u(Wop[p * C_ + n0], y, z0);
    z1 = fdot2u(Wop[p * C_ + n1], y, z1);
    z2 = fdot2u(Wop[p * C_ + n2], y, z2);
    z3 = fdot2u(Wop[p * C_ + n3c], y, z3);
  }
  z0 += bo[n0]; z1 += bo[n1]; z2 += bo[n2]; z3 += bo[n3c];
  float mx = fmaxf(fmaxf(z0, z1), z2);
  if (v3) mx = fmaxf(mx, z3);
  #pragma unroll
  for (int o = 1; o < 64; o <<= 1) mx = fmaxf(mx, __shfl_xor(mx, o));
  if ((tid & 63) == 0) redm[tid >> 6] = mx;
  __syncthreads();
  mx = fmaxf(fmaxf(redm[0], redm[1]), fmaxf(redm[2], redm[3]));
  float e0 = __expf(z0 - mx), e1 = __expf(z1 - mx), e2 = __expf(z2 - mx);
  float e3 = v3 ? __expf(z3 - mx) : 0.f;
  float s = e0 + e1 + e2 + e3;
  #pragma unroll
  for (int o = 1; o < 64; o <<= 1) s += __shfl_xor(s, o);
  if ((tid & 63) == 0) reds[tid >> 6] = s;
  __syncthreads();
  s = reds[0] + reds[1] + reds[2] + reds[3];
  float inv = 1.0f / s;
  out[b * C_ + n0] = e0 * inv;
  out[b * C_ + n1] = e1 * inv;
  out[b * C_ + n2] = e2 * inv;
  if (v3) out[b * C_ + n3] = e3 * inv;
}

extern "C" void kernel_launch(void* const* d_in, const int* in_sizes, int n_in,
                              void* d_out, int out_size, void* d_ws, size_t ws_size,
                              hipStream_t stream) {
  const int*   tokens = (const int*)d_in[0];
  const float* emb    = (const float*)d_in[1];
  const float* Wx     = (const float*)d_in[2];
  const float* Wh     = (const float*)d_in[3];
  const float* brnn   = (const float*)d_in[4];
  const float* W1     = (const float*)d_in[5];
  const float* b1     = (const float*)d_in[6];
  const float* W2     = (const float*)d_in[7];
  const float* b2     = (const float*)d_in[8];
  const float* Wo     = (const float*)d_in[9];
  const float* bo     = (const float*)d_in[10];
  float* out = (float*)d_out;

  char* ws = (char*)d_ws;
  size_t off = 0;
  auto alloc = [&](size_t bytes) -> void* {
    void* p = ws + off;
    off += (bytes + 255) & ~(size_t)255;
    return p;
  };
  u16* Xg     = (u16*)alloc((size_t)32768 * 512 * 2);   // gathered emb, bf16
  u16* WxT    = (u16*)alloc((size_t)512 * 512 * 2);     // Wx transposed, bf16
  u16* xproj  = (u16*)alloc((size_t)32768 * 512 * 2);   // x@Wx + b, f16
  u32* Wreg   = (u32*)alloc((size_t)100 * 1024 * 4);    // Wh reg-part, half2
  uint4* Wres = (uint4*)alloc((size_t)7 * 1024 * 16);   // Wh LDS-part, half2
  u32* W1p    = (u32*)alloc((size_t)256 * 1024 * 4);
  u32* W2p    = (u32*)alloc((size_t)512 * 1024 * 4);
  u32* Wop    = (u32*)alloc((size_t)512 * 1000 * 4);
  u32* hpack  = (u32*)alloc((size_t)64 * 256 * 4);
  u32* y1p    = (u32*)alloc((size_t)64 * 512 * 4);
  u32* y2p    = (u32*)alloc((size_t)64 * 512 * 4);

  k_gather<<<dim3(8192), dim3(256), 0, stream>>>(tokens, emb, Xg);
  k_trans_cvt<<<dim3(64), dim3(256), 0, stream>>>(Wx, WxT);
  k_prep_wh<<<dim3(512), dim3(256), 0, stream>>>(Wh, Wreg, (u32*)Wres);
  k_pack_pairs<<<dim3(4, 256), dim3(256), 0, stream>>>(W1, W1p, 1024);
  k_pack_pairs<<<dim3(4, 512), dim3(256), 0, stream>>>(W2, W2p, 1024);
  k_pack_pairs<<<dim3(4, 512), dim3(256), 0, stream>>>(Wo, Wop, 1000);
  k_gemm<<<dim3(256, 4), dim3(256), 0, stream>>>(Xg, WxT, brnn, xproj);
  k_rnn<<<dim3(64), dim3(1024), 0, stream>>>(Wreg, Wres, xproj, tokens, hpack);
  k_fc1<<<dim3(4, 64), dim3(256), 0, stream>>>(hpack, W1p, b1, y1p);
  k_fc2<<<dim3(4, 64), dim3(256), 0, stream>>>(y1p, W2p, b2, y2p);
  k_out<<<dim3(64), dim3(256), 0, stream>>>(y2p, Wop, bo, out);
}